// Round 6
// baseline (509.841 us; speedup 1.0000x reference)
//
#include <hip/hip_runtime.h>

// out[M,N] = x[M,K] @ W_eff[N,K]^T + bias[N],  W_eff = W + 2.0*(B@A)
// M=8192, N=4096, K=4096, R=16.
// Round 6: balanced 8/8/8/0 ds_read distribution via kk-split MFMA groups;
// staging B(kt+1)@P1, A(kt+2)@P4, vmcnt(4)/tile; 2-tile unroll (template
// literal buffers); 7 barriers/tile. T1 XCD swizzle, T2 XOR swizzle, T5 prio.

typedef __attribute__((ext_vector_type(4))) float f32x4;
typedef __attribute__((ext_vector_type(8))) short bf16x8;

__device__ __forceinline__ unsigned short f2bf(float f) {
    unsigned u = __builtin_bit_cast(unsigned, f);
    unsigned r = u + 0x7fffu + ((u >> 16) & 1u);
    return (unsigned short)(r >> 16);
}

__device__ __forceinline__ void gload_lds16(const void* g, void* l) {
    __builtin_amdgcn_global_load_lds(
        (const __attribute__((address_space(1))) void*)g,
        (__attribute__((address_space(3))) void*)l, 16, 0, 0);
}

// ---------------- cast x (f32 -> bf16) ----------------
__global__ __launch_bounds__(256) void cast_x_kernel(
    const float* __restrict__ x, unsigned short* __restrict__ xb, int n8)
{
    int stride = gridDim.x * blockDim.x;
    for (int i = blockIdx.x * blockDim.x + threadIdx.x; i < n8; i += stride) {
        size_t base = (size_t)i * 8;
        float4 f0 = *(const float4*)&x[base];
        float4 f1 = *(const float4*)&x[base + 4];
        ushort4 o0, o1;
        o0.x = f2bf(f0.x); o0.y = f2bf(f0.y); o0.z = f2bf(f0.z); o0.w = f2bf(f0.w);
        o1.x = f2bf(f1.x); o1.y = f2bf(f1.y); o1.z = f2bf(f1.z); o1.w = f2bf(f1.w);
        *(ushort4*)&xb[base]     = o0;
        *(ushort4*)&xb[base + 4] = o1;
    }
}

// ------------- W_eff = W + scale*(B@A), cast to bf16 -------------
__global__ __launch_bounds__(256) void prep_w_kernel(
    const float* __restrict__ W, const float* __restrict__ A,
    const float* __restrict__ Bl, unsigned short* __restrict__ wb,
    int K, float scale)
{
    __shared__ float Bs[16][16];
    const int t = threadIdx.x;
    const int n0 = blockIdx.y * 16;
    const int k0 = blockIdx.x * 256;
    {
        int nl = t >> 4, r = t & 15;
        Bs[nl][r] = Bl[(size_t)(n0 + nl) * 16 + r];
    }
    __syncthreads();

    const int lane = t & 63;
    const int wv = t >> 6;
    const int k = k0 + lane * 4;

    float4 av[16];
#pragma unroll
    for (int r = 0; r < 16; ++r)
        av[r] = *(const float4*)&A[(size_t)r * K + k];

#pragma unroll
    for (int j = 0; j < 4; ++j) {
        const int nl = wv * 4 + j;
        const int n = n0 + nl;
        float4 w = *(const float4*)&W[(size_t)n * K + k];
        float d0 = 0.f, d1 = 0.f, d2 = 0.f, d3 = 0.f;
#pragma unroll
        for (int r = 0; r < 16; ++r) {
            float b = Bs[nl][r];
            d0 += b * av[r].x; d1 += b * av[r].y;
            d2 += b * av[r].z; d3 += b * av[r].w;
        }
        ushort4 o;
        o.x = f2bf(w.x + scale * d0);
        o.y = f2bf(w.y + scale * d1);
        o.z = f2bf(w.z + scale * d2);
        o.w = f2bf(w.w + scale * d3);
        *(ushort4*)&wb[(size_t)n * K + k] = o;
    }
}

// ---------------- 256x256 bf16 GEMM + bias, balanced 4-phase ----------------
// 512 threads = 8 waves (2 M x 4 N), each wave owns 128x64 output.
// LDS [dbuf][A/B][half][128*64 bf16] = 128 KiB. BK=64.
// Swizzle: byte ^= (row&7)<<4 via pre-swizzled global source + swizzled read.

#define SETPRIO(p) __builtin_amdgcn_s_setprio(p)
#define BARRIER()  __builtin_amdgcn_s_barrier()
#define LGKM0()    asm volatile("s_waitcnt lgkmcnt(0)" ::: "memory")

#define ST_A(buf, h, i, ktt)                                                    \
    gload_lds16(Xb + gA[h][i] + (ktt) * 64,                                     \
                &lds[buf][0][h][(i) * 4096 + wave * 512]);
#define ST_B(buf, h, i, ktt)                                                    \
    gload_lds16(Wb + gB[h][i] + (ktt) * 64,                                     \
                &lds[buf][1][h][(i) * 4096 + wave * 512]);

#define MFMA16(ACC_ROW, AV, BV)                                                 \
    _Pragma("unroll") for (int mi = 0; mi < 4; ++mi)                            \
    _Pragma("unroll") for (int ni = 0; ni < 4; ++ni)                            \
        acc[(ACC_ROW) + mi][ni] = __builtin_amdgcn_mfma_f32_16x16x32_bf16(      \
            AV[mi], BV[ni], acc[(ACC_ROW) + mi][ni], 0, 0, 0);

template<int CUR>
__device__ __forceinline__ void ktile(
    int kt, int NT,
    unsigned short (*lds)[2][2][8192],
    f32x4 (&acc)[8][4],
    const unsigned short* __restrict__ Xb, const unsigned short* __restrict__ Wb,
    const unsigned (&gA)[2][2], const unsigned (&gB)[2][2],
    int wave, int wr, int wch, int fr, int lo0, int lo1, int bro)
{
    const char* pA = (const char*)&lds[CUR][0][wr][0];
    const char* pB = (const char*)&lds[CUR][1][wch][0];
    bf16x8 ak[4], an[4], bk[4];

    // ---- P1: reads a0-3k0 + b0-3k0 (8); stage B(kt+1)->buf[CUR^1]; G1 ----
#pragma unroll
    for (int i = 0; i < 4; ++i)
        ak[i] = *(const bf16x8*)(pA + (i * 16 + fr) * 128 + lo0);
#pragma unroll
    for (int i = 0; i < 4; ++i)
        bk[i] = *(const bf16x8*)(pB + (bro + i * 16 + fr) * 128 + lo0);
    if (kt + 1 < NT) {
        ST_B(CUR ^ 1, 0, 0, kt + 1) ST_B(CUR ^ 1, 0, 1, kt + 1)
        ST_B(CUR ^ 1, 1, 0, kt + 1) ST_B(CUR ^ 1, 1, 1, kt + 1)
    }
    BARRIER();
    LGKM0();
    SETPRIO(1);
    MFMA16(0, ak, bk)
    SETPRIO(0);
    BARRIER();

    // ---- P2: reads a4-7k0 + a0-3k1 (8); G2 = a4-7k0 x bk0 ----
#pragma unroll
    for (int i = 0; i < 4; ++i)
        an[i] = *(const bf16x8*)(pA + ((4 + i) * 16 + fr) * 128 + lo0);
#pragma unroll
    for (int i = 0; i < 4; ++i)
        ak[i] = *(const bf16x8*)(pA + (i * 16 + fr) * 128 + lo1);
    BARRIER();
    LGKM0();
    SETPRIO(1);
    MFMA16(4, an, bk)
    SETPRIO(0);
    BARRIER();

    // ---- P3: reads a4-7k1 + b0-3k1 (8); G3 = a0-3k1 x bk1 ----
#pragma unroll
    for (int i = 0; i < 4; ++i)
        an[i] = *(const bf16x8*)(pA + ((4 + i) * 16 + fr) * 128 + lo1);
#pragma unroll
    for (int i = 0; i < 4; ++i)
        bk[i] = *(const bf16x8*)(pB + (bro + i * 16 + fr) * 128 + lo1);
    BARRIER();
    LGKM0();
    SETPRIO(1);
    MFMA16(0, ak, bk)
    SETPRIO(0);
    BARRIER();

    // ---- P4: stage A(kt+2)->buf[CUR]; G4 = a4-7k1 x bk1; vmcnt(4) ----
    if (kt + 2 < NT) {
        ST_A(CUR, 0, 0, kt + 2) ST_A(CUR, 0, 1, kt + 2)
        ST_A(CUR, 1, 0, kt + 2) ST_A(CUR, 1, 1, kt + 2)
    }
    SETPRIO(1);
    MFMA16(4, an, bk)
    SETPRIO(0);
    if (kt + 2 < NT) {   // leave only A(kt+2) in flight; kt+1 fully landed
        asm volatile("s_waitcnt vmcnt(4)" ::: "memory");
    } else {
        asm volatile("s_waitcnt vmcnt(0)" ::: "memory");
    }
    BARRIER();
}

__global__ __launch_bounds__(512, 2) void gemm256_kernel(
    const unsigned short* __restrict__ Xb, const unsigned short* __restrict__ Wb,
    const float* __restrict__ bias, float* __restrict__ out,
    int M, int N, int K)
{
    __shared__ __align__(16) unsigned short lds[2][2][2][8192];

    const int NT = K / 64;
    const int ntn = N / 256;
    int bid = blockIdx.x;
    {   // XCD swizzle (grid 512, divisible by 8 -> simple form bijective)
        int per = gridDim.x >> 3;
        bid = (bid & 7) * per + (bid >> 3);
    }
    const int tm = bid / ntn, tn = bid % ntn;

    const int t = threadIdx.x;
    const int lane = t & 63, wave = t >> 6;
    const int wr = wave >> 2;          // 0..1 -> A half, rows wr*128
    const int wc = wave & 3;           // 0..3 -> cols wc*64
    const int wch = wc >> 1;           // B half
    const int bro = (wc & 1) * 64;     // B row offset within half

    // ---- staging addresses (pre-swizzled global source, linear LDS dest) ----
    const int srow = t >> 3;                                   // 0..63
    const int scol = ((t & 7) * 8) ^ (((t >> 3) & 7) << 3);    // elements
    unsigned gA[2][2], gB[2][2];
#pragma unroll
    for (int h = 0; h < 2; ++h)
#pragma unroll
        for (int i = 0; i < 2; ++i) {
            gA[h][i] = (unsigned)((tm * 256 + h * 128 + i * 64 + srow) * K + scol);
            gB[h][i] = (unsigned)((tn * 256 + h * 128 + i * 64 + srow) * K + scol);
        }

    // ---- fragment read offsets (swizzled) ----
    const int fr = lane & 15;
    const int hi16 = ((lane >> 4) & 3) * 16;       // k-offset bytes within row
    const int bsw = (fr & 7) << 4;
    const int lo0 = hi16 ^ bsw;                    // kk=0
    const int lo1 = (64 + hi16) ^ bsw;             // kk=1

    f32x4 acc[8][4] = {};

    // ---- prologue: A0,B0 -> buf0 (8); A1 -> buf1 (4); vmcnt(4) ----
#pragma unroll
    for (int h = 0; h < 2; ++h)
#pragma unroll
        for (int i = 0; i < 2; ++i) { ST_A(0, h, i, 0) ST_B(0, h, i, 0) }
#pragma unroll
    for (int h = 0; h < 2; ++h)
#pragma unroll
        for (int i = 0; i < 2; ++i) { ST_A(1, h, i, 1) }
    asm volatile("s_waitcnt vmcnt(4)" ::: "memory");   // tile0 landed, A1 flying
    BARRIER();

    for (int kt = 0; kt < NT; kt += 2) {
        ktile<0>(kt,     NT, lds, acc, Xb, Wb, gA, gB, wave, wr, wch, fr, lo0, lo1, bro);
        ktile<1>(kt + 1, NT, lds, acc, Xb, Wb, gA, gB, wave, wr, wch, fr, lo0, lo1, bro);
    }

    // ---- epilogue: C/D layout col=lane&15, row=(lane>>4)*4+reg ----
    const int row0 = tm * 256 + wr * 128 + (lane >> 4) * 4;
    const int col0 = tn * 256 + wc * 64;
#pragma unroll
    for (int ni = 0; ni < 4; ++ni) {
        const int col = col0 + ni * 16 + fr;
        const float bv = bias[col];
#pragma unroll
        for (int mi = 0; mi < 8; ++mi) {
            const int row = row0 + mi * 16;
#pragma unroll
            for (int r = 0; r < 4; ++r)
                out[(size_t)(row + r) * N + col] = acc[mi][ni][r] + bv;
        }
    }
}

extern "C" void kernel_launch(void* const* d_in, const int* in_sizes, int n_in,
                              void* d_out, int out_size, void* d_ws, size_t ws_size,
                              hipStream_t stream)
{
    const float* x  = (const float*)d_in[0];
    const float* W  = (const float*)d_in[1];
    const float* b  = (const float*)d_in[2];
    const float* A  = (const float*)d_in[3];
    const float* Bl = (const float*)d_in[4];
    float* out = (float*)d_out;

    const int Dout = in_sizes[2];
    const int Din  = in_sizes[1] / Dout;
    const int M    = in_sizes[0] / Din;

    unsigned short* xb = (unsigned short*)d_ws;
    unsigned short* wb = xb + (size_t)M * Din;

    cast_x_kernel<<<2048, 256, 0, stream>>>(x, xb, M * Din / 8);

    dim3 gw(Din / 256, Dout / 16);
    prep_w_kernel<<<gw, 256, 0, stream>>>(W, A, Bl, wb, Din, 2.0f);

    const int grid = (M / 256) * (Dout / 256); // 512
    gemm256_kernel<<<grid, 512, 0, stream>>>(xb, wb, b, out, M, Dout, Din);
}

// Round 7
// 321.359 us; speedup vs baseline: 1.5865x; 1.5865x over previous
//
#include <hip/hip_runtime.h>

// out[M,N] = x[M,K] @ W_eff[N,K]^T + bias[N],  W_eff = W + 2.0*(B@A)
// M=8192, N=4096, K=4096, R=16.
// Round 7: R4's verified schedule (best: 271us) with MFMA shape swapped to
// 32x32x16 (higher ceiling: 2382 vs 2075 TF; 4x fewer MFMA instrs).
// Phases = C-quadrants: P1 (a-blk01+b-nb0 reads, 12), P2 (a-blk23, 8),
// P3 (b-nb1, 4), P4 (0). Staging B(kt+1)@P1/P2, A(kt+2)@P3/P4, vmcnt(4)
// once per tile. T1 XCD swizzle, T2 XOR swizzle, T5 setprio.

typedef __attribute__((ext_vector_type(4)))  float f32x4;
typedef __attribute__((ext_vector_type(16))) float f32x16;
typedef __attribute__((ext_vector_type(8)))  short bf16x8;

__device__ __forceinline__ unsigned short f2bf(float f) {
    unsigned u = __builtin_bit_cast(unsigned, f);
    unsigned r = u + 0x7fffu + ((u >> 16) & 1u);
    return (unsigned short)(r >> 16);
}

__device__ __forceinline__ void gload_lds16(const void* g, void* l) {
    __builtin_amdgcn_global_load_lds(
        (const __attribute__((address_space(1))) void*)g,
        (__attribute__((address_space(3))) void*)l, 16, 0, 0);
}

// ---------------- cast x (f32 -> bf16) ----------------
__global__ __launch_bounds__(256) void cast_x_kernel(
    const float* __restrict__ x, unsigned short* __restrict__ xb, int n8)
{
    int stride = gridDim.x * blockDim.x;
    for (int i = blockIdx.x * blockDim.x + threadIdx.x; i < n8; i += stride) {
        size_t base = (size_t)i * 8;
        float4 f0 = *(const float4*)&x[base];
        float4 f1 = *(const float4*)&x[base + 4];
        ushort4 o0, o1;
        o0.x = f2bf(f0.x); o0.y = f2bf(f0.y); o0.z = f2bf(f0.z); o0.w = f2bf(f0.w);
        o1.x = f2bf(f1.x); o1.y = f2bf(f1.y); o1.z = f2bf(f1.z); o1.w = f2bf(f1.w);
        *(ushort4*)&xb[base]     = o0;
        *(ushort4*)&xb[base + 4] = o1;
    }
}

// ------------- W_eff = W + scale*(B@A), cast to bf16 -------------
__global__ __launch_bounds__(256) void prep_w_kernel(
    const float* __restrict__ W, const float* __restrict__ A,
    const float* __restrict__ Bl, unsigned short* __restrict__ wb,
    int K, float scale)
{
    __shared__ float Bs[16][16];
    const int t = threadIdx.x;
    const int n0 = blockIdx.y * 16;
    const int k0 = blockIdx.x * 256;
    {
        int nl = t >> 4, r = t & 15;
        Bs[nl][r] = Bl[(size_t)(n0 + nl) * 16 + r];
    }
    __syncthreads();

    const int lane = t & 63;
    const int wv = t >> 6;
    const int k = k0 + lane * 4;

    float4 av[16];
#pragma unroll
    for (int r = 0; r < 16; ++r)
        av[r] = *(const float4*)&A[(size_t)r * K + k];

#pragma unroll
    for (int j = 0; j < 4; ++j) {
        const int nl = wv * 4 + j;
        const int n = n0 + nl;
        float4 w = *(const float4*)&W[(size_t)n * K + k];
        float d0 = 0.f, d1 = 0.f, d2 = 0.f, d3 = 0.f;
#pragma unroll
        for (int r = 0; r < 16; ++r) {
            float b = Bs[nl][r];
            d0 += b * av[r].x; d1 += b * av[r].y;
            d2 += b * av[r].z; d3 += b * av[r].w;
        }
        ushort4 o;
        o.x = f2bf(w.x + scale * d0);
        o.y = f2bf(w.y + scale * d1);
        o.z = f2bf(w.z + scale * d2);
        o.w = f2bf(w.w + scale * d3);
        *(ushort4*)&wb[(size_t)n * K + k] = o;
    }
}

// ---------------- 256x256 bf16 GEMM + bias, 32x32x16 MFMA ----------------
// 512 threads = 8 waves (2 M x 4 N), each wave owns 128x64 output as
// 4x2 tiles of 32x32. LDS [dbuf][A/B][half][128*64 bf16] = 128 KiB. BK=64.
// Swizzle: byte ^= (row&7)<<4 via pre-swizzled global source + swizzled read.

#define SETPRIO(p) __builtin_amdgcn_s_setprio(p)
#define BARRIER()  __builtin_amdgcn_s_barrier()
#define LGKM0()    do { asm volatile("s_waitcnt lgkmcnt(0)" ::: "memory"); \
                        __builtin_amdgcn_sched_barrier(0); } while (0)

__global__ __launch_bounds__(512, 2) void gemm256_kernel(
    const unsigned short* __restrict__ Xb, const unsigned short* __restrict__ Wb,
    const float* __restrict__ bias, float* __restrict__ out,
    int M, int N, int K)
{
    __shared__ __align__(16) unsigned short lds[2][2][2][8192];

    const int NT = K / 64;
    const int ntn = N / 256;
    int bid = blockIdx.x;
    {   // XCD swizzle (grid 512, divisible by 8 -> simple form bijective)
        int per = gridDim.x >> 3;
        bid = (bid & 7) * per + (bid >> 3);
    }
    const int tm = bid / ntn, tn = bid % ntn;

    const int t = threadIdx.x;
    const int lane = t & 63, wave = t >> 6;
    const int wr = wave >> 2;          // 0..1 -> A half, rows wr*128
    const int wc = wave & 3;           // 0..3 -> cols wc*64
    const int wch = wc >> 1;           // B half
    const int bro = (wc & 1) * 64;     // B row offset within half

    // ---- staging addresses (pre-swizzled global source, linear LDS dest) ----
    const int srow = t >> 3;                                   // 0..63
    const int scol = ((t & 7) * 8) ^ (((t >> 3) & 7) << 3);    // elements
    unsigned gA[2][2], gB[2][2];
#pragma unroll
    for (int h = 0; h < 2; ++h)
#pragma unroll
        for (int i = 0; i < 2; ++i) {
            gA[h][i] = (unsigned)((tm * 256 + h * 128 + i * 64 + srow) * K + scol);
            gB[h][i] = (unsigned)((tn * 256 + h * 128 + i * 64 + srow) * K + scol);
        }

#define ST_A(buf, h, i, ktt)                                                    \
    gload_lds16(Xb + gA[h][i] + (ktt) * 64,                                     \
                &lds[buf][0][h][(i) * 4096 + wave * 512]);
#define ST_B(buf, h, i, ktt)                                                    \
    gload_lds16(Wb + gB[h][i] + (ktt) * 64,                                     \
                &lds[buf][1][h][(i) * 4096 + wave * 512]);

    // ---- fragment read offsets (swizzled), 32x32x16 layout ----
    // A-frag: row = blk*32 + (lane&31), k = kq*16 + (lane>>5)*8 .. +7
    const int r32 = lane & 31;
    const int hi2 = lane >> 5;
    const int bsw = (r32 & 7) << 4;
    int koff[4];
#pragma unroll
    for (int kq = 0; kq < 4; ++kq)
        koff[kq] = (kq * 32 + hi2 * 16) ^ bsw;     // byte offset within row

    f32x16 acc[4][2] = {};

    // ---- prologue: A0,B0 -> buf0 (8); A1 -> buf1 (4); vmcnt(4) ----
#pragma unroll
    for (int h = 0; h < 2; ++h)
#pragma unroll
        for (int i = 0; i < 2; ++i) { ST_A(0, h, i, 0) ST_B(0, h, i, 0) }
#pragma unroll
    for (int h = 0; h < 2; ++h)
#pragma unroll
        for (int i = 0; i < 2; ++i) { ST_A(1, h, i, 1) }
    asm volatile("s_waitcnt vmcnt(4)" ::: "memory");   // tile0 landed, A1 flying
    BARRIER();

#define MFMA_PAIR(mb0, nb)                                                      \
    _Pragma("unroll") for (int kq = 0; kq < 4; ++kq) {                          \
        acc[mb0][nb] = __builtin_amdgcn_mfma_f32_32x32x16_bf16(                 \
            a[mb0][kq], b[nb][kq], acc[mb0][nb], 0, 0, 0);                      \
        acc[mb0 + 1][nb] = __builtin_amdgcn_mfma_f32_32x32x16_bf16(             \
            a[mb0 + 1][kq], b[nb][kq], acc[mb0 + 1][nb], 0, 0, 0);              \
    }

    for (int kt = 0; kt < NT; ++kt) {
        const int cur = kt & 1;
        const char* pA = (const char*)&lds[cur][0][wr][0];
        const char* pB = (const char*)&lds[cur][1][wch][0];
        const bool stB = (kt + 1 < NT);  // B of kt+1 -> buf[cur^1]
        const bool stA = (kt + 2 < NT);  // A of kt+2 -> buf[cur]

        bf16x8 a[4][4], b[2][4];

        // ---- P1: read a-blk0,1 (8) + b-nb0 (4); stage B-h0(kt+1); MFMA ----
#pragma unroll
        for (int mb = 0; mb < 2; ++mb)
#pragma unroll
            for (int kq = 0; kq < 4; ++kq)
                a[mb][kq] = *(const bf16x8*)(pA + (mb * 32 + r32) * 128 + koff[kq]);
#pragma unroll
        for (int kq = 0; kq < 4; ++kq)
            b[0][kq] = *(const bf16x8*)(pB + (bro + r32) * 128 + koff[kq]);
        if (stB) { ST_B(cur ^ 1, 0, 0, kt + 1) ST_B(cur ^ 1, 0, 1, kt + 1) }
        BARRIER();
        LGKM0();
        SETPRIO(1);
        MFMA_PAIR(0, 0)
        SETPRIO(0);
        BARRIER();

        // ---- P2: read a-blk2,3 (8); stage B-h1(kt+1); MFMA (2,0),(3,0) ----
#pragma unroll
        for (int mb = 2; mb < 4; ++mb)
#pragma unroll
            for (int kq = 0; kq < 4; ++kq)
                a[mb][kq] = *(const bf16x8*)(pA + (mb * 32 + r32) * 128 + koff[kq]);
        if (stB) { ST_B(cur ^ 1, 1, 0, kt + 1) ST_B(cur ^ 1, 1, 1, kt + 1) }
        BARRIER();
        LGKM0();
        SETPRIO(1);
        MFMA_PAIR(2, 0)
        SETPRIO(0);
        BARRIER();
        // A[cur] fully consumed by all waves from here.

        // ---- P3: read b-nb1 (4); stage A-h0(kt+2); MFMA (0,1),(1,1) ----
#pragma unroll
        for (int kq = 0; kq < 4; ++kq)
            b[1][kq] = *(const bf16x8*)(pB + (bro + 32 + r32) * 128 + koff[kq]);
        if (stA) { ST_A(cur, 0, 0, kt + 2) ST_A(cur, 0, 1, kt + 2) }
        BARRIER();
        LGKM0();
        SETPRIO(1);
        MFMA_PAIR(0, 1)
        SETPRIO(0);
        BARRIER();
        // B[cur] fully consumed by all waves from here.

        // ---- P4: stage A-h1(kt+2); MFMA (2,1),(3,1); counted vmcnt ----
        if (stA) { ST_A(cur, 1, 0, kt + 2) ST_A(cur, 1, 1, kt + 2) }
        BARRIER();
        SETPRIO(1);
        MFMA_PAIR(2, 1)
        SETPRIO(0);
        if (stA) {   // leave only A(kt+2)'s 4 loads in flight
            asm volatile("s_waitcnt vmcnt(4)" ::: "memory");
        } else {
            asm volatile("s_waitcnt vmcnt(0)" ::: "memory");
        }
        BARRIER();
    }

    // ---- epilogue: 32x32 C/D: col=lane&31, row=(reg&3)+8*(reg>>2)+4*(lane>>5)
    const int row0 = tm * 256 + wr * 128 + hi2 * 4;
    const int col0 = tn * 256 + wc * 64 + r32;
#pragma unroll
    for (int nb = 0; nb < 2; ++nb) {
        const int col = col0 + nb * 32;
        const float bv = bias[col];
#pragma unroll
        for (int mb = 0; mb < 4; ++mb) {
            const f32x16 v = acc[mb][nb];
#pragma unroll
            for (int r = 0; r < 16; ++r) {
                const int row = row0 + mb * 32 + (r & 3) + 8 * (r >> 2);
                out[(size_t)row * N + col] = v[r] + bv;
            }
        }
    }
}

extern "C" void kernel_launch(void* const* d_in, const int* in_sizes, int n_in,
                              void* d_out, int out_size, void* d_ws, size_t ws_size,
                              hipStream_t stream)
{
    const float* x  = (const float*)d_in[0];
    const float* W  = (const float*)d_in[1];
    const float* b  = (const float*)d_in[2];
    const float* A  = (const float*)d_in[3];
    const float* Bl = (const float*)d_in[4];
    float* out = (float*)d_out;

    const int Dout = in_sizes[2];
    const int Din  = in_sizes[1] / Dout;
    const int M    = in_sizes[0] / Din;

    unsigned short* xb = (unsigned short*)d_ws;
    unsigned short* wb = xb + (size_t)M * Din;

    cast_x_kernel<<<2048, 256, 0, stream>>>(x, xb, M * Din / 8);

    dim3 gw(Din / 256, Dout / 16);
    prep_w_kernel<<<gw, 256, 0, stream>>>(W, A, Bl, wb, Din, 2.0f);

    const int grid = (M / 256) * (Dout / 256); // 512
    gemm256_kernel<<<grid, 512, 0, stream>>>(xb, wb, b, out, M, Dout, Din);
}

// Round 8
// 319.816 us; speedup vs baseline: 1.5942x; 1.0048x over previous
//
#include <hip/hip_runtime.h>

// out[M,N] = x[M,K] @ W_eff[N,K]^T + bias[N],  W_eff = W + 2.0*(B@A)
// M=8192, N=4096, K=4096, R=16.
// Round 8: fat register tiles — 4 waves x (128x128 out each), 32x32x16 MFMA.
// Per-CU LDS traffic drops 192->128 KB/K-tile (reads/MFMA 0.75->0.5), making
// the kernel MFMA-bound (1536 < 2064 cyc). R4-proven phase schedule:
// quadrant phases, B(t+1)@P1/P2, A(t+2)@P3/P4, vmcnt(8)/tile, T1/T2/T5.
// VGPR ~384 -> __launch_bounds__(256,1).

typedef __attribute__((ext_vector_type(4)))  float f32x4;
typedef __attribute__((ext_vector_type(16))) float f32x16;
typedef __attribute__((ext_vector_type(8)))  short bf16x8;

__device__ __forceinline__ unsigned short f2bf(float f) {
    unsigned u = __builtin_bit_cast(unsigned, f);
    unsigned r = u + 0x7fffu + ((u >> 16) & 1u);
    return (unsigned short)(r >> 16);
}

__device__ __forceinline__ void gload_lds16(const void* g, void* l) {
    __builtin_amdgcn_global_load_lds(
        (const __attribute__((address_space(1))) void*)g,
        (__attribute__((address_space(3))) void*)l, 16, 0, 0);
}

// ---------------- cast x (f32 -> bf16) ----------------
__global__ __launch_bounds__(256) void cast_x_kernel(
    const float* __restrict__ x, unsigned short* __restrict__ xb, int n8)
{
    int stride = gridDim.x * blockDim.x;
    for (int i = blockIdx.x * blockDim.x + threadIdx.x; i < n8; i += stride) {
        size_t base = (size_t)i * 8;
        float4 f0 = *(const float4*)&x[base];
        float4 f1 = *(const float4*)&x[base + 4];
        ushort4 o0, o1;
        o0.x = f2bf(f0.x); o0.y = f2bf(f0.y); o0.z = f2bf(f0.z); o0.w = f2bf(f0.w);
        o1.x = f2bf(f1.x); o1.y = f2bf(f1.y); o1.z = f2bf(f1.z); o1.w = f2bf(f1.w);
        *(ushort4*)&xb[base]     = o0;
        *(ushort4*)&xb[base + 4] = o1;
    }
}

// ------------- W_eff = W + scale*(B@A), cast to bf16 -------------
__global__ __launch_bounds__(256) void prep_w_kernel(
    const float* __restrict__ W, const float* __restrict__ A,
    const float* __restrict__ Bl, unsigned short* __restrict__ wb,
    int K, float scale)
{
    __shared__ float Bs[16][16];
    const int t = threadIdx.x;
    const int n0 = blockIdx.y * 16;
    const int k0 = blockIdx.x * 256;
    {
        int nl = t >> 4, r = t & 15;
        Bs[nl][r] = Bl[(size_t)(n0 + nl) * 16 + r];
    }
    __syncthreads();

    const int lane = t & 63;
    const int wv = t >> 6;
    const int k = k0 + lane * 4;

    float4 av[16];
#pragma unroll
    for (int r = 0; r < 16; ++r)
        av[r] = *(const float4*)&A[(size_t)r * K + k];

#pragma unroll
    for (int j = 0; j < 4; ++j) {
        const int nl = wv * 4 + j;
        const int n = n0 + nl;
        float4 w = *(const float4*)&W[(size_t)n * K + k];
        float d0 = 0.f, d1 = 0.f, d2 = 0.f, d3 = 0.f;
#pragma unroll
        for (int r = 0; r < 16; ++r) {
            float b = Bs[nl][r];
            d0 += b * av[r].x; d1 += b * av[r].y;
            d2 += b * av[r].z; d3 += b * av[r].w;
        }
        ushort4 o;
        o.x = f2bf(w.x + scale * d0);
        o.y = f2bf(w.y + scale * d1);
        o.z = f2bf(w.z + scale * d2);
        o.w = f2bf(w.w + scale * d3);
        *(ushort4*)&wb[(size_t)n * K + k] = o;
    }
}

// ---------------- 256x256 bf16 GEMM + bias, 4 waves x 128x128 ----------------
// 256 threads = 4 waves (2M x 2N). LDS [dbuf][A/B][half][128*64 bf16] = 128 KiB.
// BK=64, 32x32x16 MFMA, wave tile = 4mb x 4nb x 4kq = 64 MFMA/K-tile.
// Swizzle: byte ^= (row&7)<<4 via pre-swizzled global source + swizzled read.

#define SETPRIO(p) __builtin_amdgcn_s_setprio(p)
#define BARRIER()  __builtin_amdgcn_s_barrier()
#define LGKM0()    do { asm volatile("s_waitcnt lgkmcnt(0)" ::: "memory"); \
                        __builtin_amdgcn_sched_barrier(0); } while (0)

__global__ __launch_bounds__(256, 1) void gemm256_kernel(
    const unsigned short* __restrict__ Xb, const unsigned short* __restrict__ Wb,
    const float* __restrict__ bias, float* __restrict__ out,
    int M, int N, int K)
{
    __shared__ __align__(16) unsigned short lds[2][2][2][8192];

    const int NT = K / 64;
    const int ntn = N / 256;
    int bid = blockIdx.x;
    {   // XCD swizzle (grid 512, divisible by 8 -> simple form bijective)
        int per = gridDim.x >> 3;
        bid = (bid & 7) * per + (bid >> 3);
    }
    const int tm = bid / ntn, tn = bid % ntn;

    const int t = threadIdx.x;
    const int lane = t & 63, wave = t >> 6;   // wave 0..3
    const int wr = wave >> 1;          // A half (rows wr*128)
    const int wc = wave & 1;           // B half (cols wc*128)

    // ---- staging addresses (pre-swizzled global source, linear LDS dest) ----
    // thread t, load j in {0,1}: row = (t>>3) + 32j, 16B k-slot (t&7)^swz
    const int srow = t >> 3;                                   // 0..31
    const int scol = ((t & 7) * 8) ^ (((t >> 3) & 7) << 3);    // elements
    unsigned gA[2][2], gB[2][2];
#pragma unroll
    for (int h = 0; h < 2; ++h)
#pragma unroll
        for (int i = 0; i < 2; ++i) {
            gA[h][i] = (unsigned)((tm * 256 + h * 128 + i * 64 + srow) * K + scol);
            gB[h][i] = (unsigned)((tn * 256 + h * 128 + i * 64 + srow) * K + scol);
        }
    const unsigned jstep = 32u * (unsigned)K;   // +32 rows

    // stage one half (128x64 = 4 loads: chunks i=0,1 x j=0,1)
#define ST_A(buf, h, ktt)                                                       \
    _Pragma("unroll") for (int i = 0; i < 2; ++i) {                             \
        gload_lds16(Xb + gA[h][i] + (ktt) * 64,                                 \
                    &lds[buf][0][h][i * 4096 + wave * 512]);                    \
        gload_lds16(Xb + gA[h][i] + jstep + (ktt) * 64,                         \
                    &lds[buf][0][h][i * 4096 + 2048 + wave * 512]);             \
    }
#define ST_B(buf, h, ktt)                                                       \
    _Pragma("unroll") for (int i = 0; i < 2; ++i) {                             \
        gload_lds16(Wb + gB[h][i] + (ktt) * 64,                                 \
                    &lds[buf][1][h][i * 4096 + wave * 512]);                    \
        gload_lds16(Wb + gB[h][i] + jstep + (ktt) * 64,                         \
                    &lds[buf][1][h][i * 4096 + 2048 + wave * 512]);             \
    }

    // ---- fragment read offsets (swizzled), 32x32x16 layout ----
    const int r32 = lane & 31;
    const int hi2 = lane >> 5;
    const int bsw = (r32 & 7) << 4;
    int koff[4];
#pragma unroll
    for (int kq = 0; kq < 4; ++kq)
        koff[kq] = (kq * 32 + hi2 * 16) ^ bsw;     // byte offset within row

    f32x16 acc[4][4] = {};

    // ---- prologue: A0,B0 -> buf0 (16); A1 -> buf1 (8); vmcnt(8) ----
#pragma unroll
    for (int h = 0; h < 2; ++h) { ST_A(0, h, 0) ST_B(0, h, 0) }
#pragma unroll
    for (int h = 0; h < 2; ++h) { ST_A(1, h, 1) }
    asm volatile("s_waitcnt vmcnt(8)" ::: "memory");   // tile0 landed, A1 flying
    BARRIER();

    // quadrant (mbp,nbp): mb in {2mbp,2mbp+1}, nb in {2nbp,2nbp+1}, kq 0..3
#define MFMA_QUAD(mbp, nbp)                                                     \
    _Pragma("unroll") for (int kq = 0; kq < 4; ++kq)                            \
    _Pragma("unroll") for (int d = 0; d < 2; ++d)                               \
    _Pragma("unroll") for (int e = 0; e < 2; ++e)                               \
        acc[2 * (mbp) + d][2 * (nbp) + e] =                                     \
            __builtin_amdgcn_mfma_f32_32x32x16_bf16(                            \
                a[2 * (mbp) + d][kq], b[2 * (nbp) + e][kq],                     \
                acc[2 * (mbp) + d][2 * (nbp) + e], 0, 0, 0);

    for (int kt = 0; kt < NT; ++kt) {
        const int cur = kt & 1;
        const char* pA = (const char*)&lds[cur][0][wr][0];
        const char* pB = (const char*)&lds[cur][1][wc][0];
        const bool stB = (kt + 1 < NT);  // B of kt+1 -> buf[cur^1]
        const bool stA = (kt + 2 < NT);  // A of kt+2 -> buf[cur]

        bf16x8 a[4][4], b[4][4];

        // ---- P1: read a0-1 (8) + b0-1 (8); stage B-h0(kt+1); Q(0,0) ----
#pragma unroll
        for (int mb = 0; mb < 2; ++mb)
#pragma unroll
            for (int kq = 0; kq < 4; ++kq)
                a[mb][kq] = *(const bf16x8*)(pA + (mb * 32 + r32) * 128 + koff[kq]);
#pragma unroll
        for (int nb = 0; nb < 2; ++nb)
#pragma unroll
            for (int kq = 0; kq < 4; ++kq)
                b[nb][kq] = *(const bf16x8*)(pB + (nb * 32 + r32) * 128 + koff[kq]);
        if (stB) { ST_B(cur ^ 1, 0, kt + 1) }
        BARRIER();
        LGKM0();
        SETPRIO(1);
        MFMA_QUAD(0, 0)
        SETPRIO(0);
        BARRIER();

        // ---- P2: read a2-3 (8); stage B-h1(kt+1); Q(1,0) ----
#pragma unroll
        for (int mb = 2; mb < 4; ++mb)
#pragma unroll
            for (int kq = 0; kq < 4; ++kq)
                a[mb][kq] = *(const bf16x8*)(pA + (mb * 32 + r32) * 128 + koff[kq]);
        if (stB) { ST_B(cur ^ 1, 1, kt + 1) }
        BARRIER();
        LGKM0();
        SETPRIO(1);
        MFMA_QUAD(1, 0)
        SETPRIO(0);
        BARRIER();
        // A[cur] fully consumed by all waves from here.

        // ---- P3: read b2-3 (8); stage A-h0(kt+2); Q(0,1) ----
#pragma unroll
        for (int nb = 2; nb < 4; ++nb)
#pragma unroll
            for (int kq = 0; kq < 4; ++kq)
                b[nb][kq] = *(const bf16x8*)(pB + (nb * 32 + r32) * 128 + koff[kq]);
        if (stA) { ST_A(cur, 0, kt + 2) }
        BARRIER();
        LGKM0();
        SETPRIO(1);
        MFMA_QUAD(0, 1)
        SETPRIO(0);
        BARRIER();
        // B[cur] fully consumed by all waves from here.

        // ---- P4: stage A-h1(kt+2); Q(1,1); counted vmcnt ----
        if (stA) { ST_A(cur, 1, kt + 2) }
        BARRIER();
        SETPRIO(1);
        MFMA_QUAD(1, 1)
        SETPRIO(0);
        if (stA) {   // leave only A(kt+2)'s 8 loads in flight
            asm volatile("s_waitcnt vmcnt(8)" ::: "memory");
        } else {
            asm volatile("s_waitcnt vmcnt(0)" ::: "memory");
        }
        BARRIER();
    }

    // ---- epilogue: 32x32 C/D: col=lane&31, row=(reg&3)+8*(reg>>2)+4*(lane>>5)
    const int row0 = tm * 256 + wr * 128 + hi2 * 4;
    const int col0 = tn * 256 + wc * 128 + r32;
#pragma unroll
    for (int nb = 0; nb < 4; ++nb) {
        const int col = col0 + nb * 32;
        const float bv = bias[col];
#pragma unroll
        for (int mb = 0; mb < 4; ++mb) {
            const f32x16 v = acc[mb][nb];
#pragma unroll
            for (int r = 0; r < 16; ++r) {
                const int row = row0 + mb * 32 + (r & 3) + 8 * (r >> 2);
                out[(size_t)row * N + col] = v[r] + bv;
            }
        }
    }
}

extern "C" void kernel_launch(void* const* d_in, const int* in_sizes, int n_in,
                              void* d_out, int out_size, void* d_ws, size_t ws_size,
                              hipStream_t stream)
{
    const float* x  = (const float*)d_in[0];
    const float* W  = (const float*)d_in[1];
    const float* b  = (const float*)d_in[2];
    const float* A  = (const float*)d_in[3];
    const float* Bl = (const float*)d_in[4];
    float* out = (float*)d_out;

    const int Dout = in_sizes[2];
    const int Din  = in_sizes[1] / Dout;
    const int M    = in_sizes[0] / Din;

    unsigned short* xb = (unsigned short*)d_ws;
    unsigned short* wb = xb + (size_t)M * Din;

    cast_x_kernel<<<2048, 256, 0, stream>>>(x, xb, M * Din / 8);

    dim3 gw(Din / 256, Dout / 16);
    prep_w_kernel<<<gw, 256, 0, stream>>>(W, A, Bl, wb, Din, 2.0f);

    const int grid = (M / 256) * (Dout / 256); // 512
    gemm256_kernel<<<grid, 256, 0, stream>>>(xb, wb, b, out, M, Dout, Din);
}